// Round 5
// baseline (4294.617 us; speedup 1.0000x reference)
//
#include <hip/hip_runtime.h>
#include <math.h>

// ---------------------------------------------------------------------------
// Round N+3 (resubmit; bench died in container acquisition both attempts —
// same infra signature as round 2, which passed unchanged on resubmit):
// all internal activations stored as bf16 hi/lo PAIRS (same 4B/elem footprint
// as fp32) so every GEMM stages plain bf16 copies instead of fp32->bf16 split
// conversion in the K-loop, and operand traffic halves.
//   producers: tri epilogue (Q/K/V pairs), softmax (P pair, in-place per row),
//   PV epilogue (cb pair), FFN1 epilogue (h1 pair), add_ln (xb pair).
//   consumers recombine hi+lo where fp32 needed (gate, residual, flash).
// MFMA body/products unchanged (hh + h*lo + lo*h). absmax expected ~0.0156.
// ---------------------------------------------------------------------------

typedef unsigned short bf16_t;
typedef __attribute__((ext_vector_type(8))) short s16x8;
typedef __attribute__((ext_vector_type(8))) unsigned short u16x8;
typedef __attribute__((ext_vector_type(4))) float f32x4;

__device__ __forceinline__ float bf2f(bf16_t u) {
    union { unsigned int i; float f; } v; v.i = ((unsigned int)u) << 16; return v.f;
}
__device__ __forceinline__ bf16_t f2bf(float f) {
    union { float f; unsigned int i; } v; v.f = f;
    unsigned int x = v.i;
    return (bf16_t)((x + 0x7fffu + ((x >> 16) & 1u)) >> 16);  // RNE
}
// hi = truncated-to-bf16 part, rem = x - hi (exact in fp32)
__device__ __forceinline__ bf16_t bfhi_trunc(float x, float& rem) {
    union { float f; unsigned u; } v; v.f = x;
    unsigned hu = v.u & 0xFFFF0000u;
    union { unsigned u; float f; } h; h.u = hu;
    rem = x - h.f;
    return (bf16_t)(hu >> 16);
}
// RNE pair split: x ~= hi + lo to ~2^-18 relative
__device__ __forceinline__ void split_rne(float x, bf16_t& hi, bf16_t& lo) {
    bf16_t h = f2bf(x);
    float hf = bf2f(h);
    lo = f2bf(x - hf);
    hi = h;
}

__device__ __forceinline__ float waveReduceSum(float x) {
    x += __shfl_xor(x, 1);  x += __shfl_xor(x, 2);  x += __shfl_xor(x, 4);
    x += __shfl_xor(x, 8);  x += __shfl_xor(x, 16); x += __shfl_xor(x, 32);
    return x;
}
__device__ __forceinline__ float waveReduceMax(float x) {
    x = fmaxf(x, __shfl_xor(x, 1));  x = fmaxf(x, __shfl_xor(x, 2));
    x = fmaxf(x, __shfl_xor(x, 4));  x = fmaxf(x, __shfl_xor(x, 8));
    x = fmaxf(x, __shfl_xor(x, 16)); x = fmaxf(x, __shfl_xor(x, 32));
    return x;
}

// ---------------- dtype probe ----------------------------------------------
__global__ void probe_kernel(const unsigned int* __restrict__ lng_u32,
                             int* __restrict__ flag)
{
    if (threadIdx.x == 0 && blockIdx.x == 0)
        *flag = (lng_u32[0] == 0x3F803F80u) ? 1 : 0;
}

// ---------------- LDS staging helpers --------------------------------------
// LDS tile row = 128 bytes: [hi bf16 k=0..31 | lo bf16 k=0..31], swizzled by
// byte ^= ((row&7)<<4). Writes and reads use the same bijection.

__device__ __forceinline__ void stage_f32_row(const float* __restrict__ src,
                                              char* rowp, int h, int r)
{
    float xx[16];
    *(float4*)(xx + 0)  = *(const float4*)(src + 0);
    *(float4*)(xx + 4)  = *(const float4*)(src + 4);
    *(float4*)(xx + 8)  = *(const float4*)(src + 8);
    *(float4*)(xx + 12) = *(const float4*)(src + 12);
    u16x8 h0, h1, l0, l1;
#pragma unroll
    for (int i = 0; i < 8; i++) {
        float r0, r1;
        h0[i] = bfhi_trunc(xx[i], r0);      l0[i] = f2bf(r0);
        h1[i] = bfhi_trunc(xx[8 + i], r1);  l1[i] = f2bf(r1);
    }
    const int sw = (r & 7) << 4;
    *(u16x8*)(rowp + ((32 * h + 0)  ^ sw)) = h0;
    *(u16x8*)(rowp + ((32 * h + 16) ^ sw)) = h1;
    *(u16x8*)(rowp + ((64 + 32 * h + 0)  ^ sw)) = l0;
    *(u16x8*)(rowp + ((64 + 32 * h + 16) ^ sw)) = l1;
}

__device__ __forceinline__ void stage_bf16_row(const bf16_t* __restrict__ src,
                                               char* rowp, int h, int r)
{
    u16x8 v0 = *(const u16x8*)(src);
    u16x8 v1 = *(const u16x8*)(src + 8);
    const int sw = (r & 7) << 4;
    *(u16x8*)(rowp + ((32 * h + 0)  ^ sw)) = v0;
    *(u16x8*)(rowp + ((32 * h + 16) ^ sw)) = v1;
}

__device__ __forceinline__ void stage_pair_row(const bf16_t* __restrict__ hi,
                                               const bf16_t* __restrict__ lo,
                                               char* rowp, int h, int r)
{
    u16x8 h0 = *(const u16x8*)(hi);
    u16x8 h1 = *(const u16x8*)(hi + 8);
    u16x8 l0 = *(const u16x8*)(lo);
    u16x8 l1 = *(const u16x8*)(lo + 8);
    const int sw = (r & 7) << 4;
    *(u16x8*)(rowp + ((32 * h + 0)  ^ sw)) = h0;
    *(u16x8*)(rowp + ((32 * h + 16) ^ sw)) = h1;
    *(u16x8*)(rowp + ((64 + 32 * h + 0)  ^ sw)) = l0;
    *(u16x8*)(rowp + ((64 + 32 * h + 16) ^ sw)) = l1;
}

// NN staging: base=0 writes hi slots, base=64 writes lo slots
__device__ __forceinline__ void stage_wnn_bf16(const bf16_t* __restrict__ src,
                                               int ldb, ushort (*Bs)[64],
                                               int kp2, int n8, int base)
{
    u16x8 r0 = *(const u16x8*)(src);
    u16x8 r1 = *(const u16x8*)(src + ldb);
#pragma unroll
    for (int j = 0; j < 8; j++) {
        int rr = n8 + j;
        unsigned v = (unsigned)(unsigned short)r0[j] |
                     ((unsigned)(unsigned short)r1[j] << 16);
        *(unsigned*)((char*)&Bs[rr][0] + ((base + 2 * kp2) ^ ((rr & 7) << 4))) = v;
    }
}

__device__ __forceinline__ void stage_wnn_f32(const float* __restrict__ src,
                                              int ldb, ushort (*Bs)[64],
                                              int kp2, int n8)
{
    float a0[8], a1[8];
    *(float4*)(a0 + 0) = *(const float4*)(src);
    *(float4*)(a0 + 4) = *(const float4*)(src + 4);
    *(float4*)(a1 + 0) = *(const float4*)(src + ldb);
    *(float4*)(a1 + 4) = *(const float4*)(src + ldb + 4);
#pragma unroll
    for (int j = 0; j < 8; j++) {
        int rr = n8 + j;
        float q0, q1;
        bf16_t h0 = bfhi_trunc(a0[j], q0);
        bf16_t h1 = bfhi_trunc(a1[j], q1);
        unsigned vh = (unsigned)h0 | ((unsigned)h1 << 16);
        unsigned vl = (unsigned)f2bf(q0) | ((unsigned)f2bf(q1) << 16);
        char* rp = (char*)&Bs[rr][0];
        int sw = (rr & 7) << 4;
        *(unsigned*)(rp + ((2 * kp2) ^ sw)) = vh;
        *(unsigned*)(rp + ((64 + 2 * kp2) ^ sw)) = vl;
    }
}

// ---------------- Unified MFMA GEMM body ------------------------------------
// am/bm: 0 = fp32 (split at stage), 1 = bf16 single (exact), 2 = bf16 pair.
template<bool NT, bool RELU, bool GATHER, bool SCALE, bool OUTP>
__device__ __forceinline__
void mgemm_body(int am, const float* __restrict__ aF,
                const bf16_t* __restrict__ aH, const bf16_t* __restrict__ aL,
                int bm, const float* __restrict__ bF,
                const bf16_t* __restrict__ bH, const bf16_t* __restrict__ bL,
                const float* __restrict__ biasF, const bf16_t* __restrict__ biasH,
                const bool bf, const bool hasb,
                float* __restrict__ Cp, bf16_t* __restrict__ CpH, long cplane,
                int lda, int ldb, int ldc,
                int Meff, const int* __restrict__ gl,
                const float* __restrict__ scalev,
                int kBeg, int kEnd, int m0, int n0)
{
    __shared__ __align__(16) ushort As[128][64];
    __shared__ __align__(16) ushort Bs[128][64];

    const int t   = threadIdx.x;
    const int sr  = t >> 1;               // staging row 0..127
    const int sh  = t & 1;                // k-half
    const int kp2 = (t & 15) * 2;         // NN staging k-pair
    const int n8  = (t >> 4) * 8;         // NN staging n-chunk

    int agr = m0 + sr;
    if (GATHER) agr = gl[(m0 + sr < Meff) ? (m0 + sr) : (Meff - 1)];

    const int lane = t & 63;
    const int wv = t >> 6;
    const int wr = wv >> 1, wc = wv & 1;
    const int lr = lane & 15, kg = lane >> 4;

    int aoffH[4], aoffL[4], boffH[4], boffL[4];
#pragma unroll
    for (int i = 0; i < 4; i++) {
        int ra = wr * 64 + i * 16 + lr;
        int sa = (ra & 7) << 4;
        aoffH[i] = ra * 128 + ((kg * 16) ^ sa);
        aoffL[i] = ra * 128 + ((64 + kg * 16) ^ sa);
        int rb = wc * 64 + i * 16 + lr;
        int sb = (rb & 7) << 4;
        boffH[i] = rb * 128 + ((kg * 16) ^ sb);
        boffL[i] = rb * 128 + ((64 + kg * 16) ^ sb);
    }

    f32x4 acc[4][4];
#pragma unroll
    for (int i = 0; i < 4; i++)
#pragma unroll
        for (int j = 0; j < 4; j++)
            acc[i][j] = (f32x4){0.f, 0.f, 0.f, 0.f};

    const bool aHasLo = (am != 1);
    const bool bHasLo = (bm != 1);

    for (int k0 = kBeg; k0 < kEnd; k0 += 32) {
        __syncthreads();
        {   // stage A
            char* rowp = (char*)&As[sr][0];
            long aoff = (long)agr * lda + k0 + sh * 16;
            if (am == 2)      stage_pair_row(aH + aoff, aL + aoff, rowp, sh, sr);
            else if (am == 1) stage_bf16_row(aH + aoff, rowp, sh, sr);
            else              stage_f32_row (aF + aoff, rowp, sh, sr);
        }
        // stage B
        if (NT) {
            char* rowp = (char*)&Bs[sr][0];
            long boff = (long)(n0 + sr) * ldb + k0 + sh * 16;
            if (bm == 2)      stage_pair_row(bH + boff, bL + boff, rowp, sh, sr);
            else if (bm == 1) stage_bf16_row(bH + boff, rowp, sh, sr);
            else              stage_f32_row (bF + boff, rowp, sh, sr);
        } else {
            long boff = (long)(k0 + kp2) * ldb + n0 + n8;
            if (bm == 2) {
                stage_wnn_bf16(bH + boff, ldb, Bs, kp2, n8, 0);
                stage_wnn_bf16(bL + boff, ldb, Bs, kp2, n8, 64);
            } else if (bm == 1) {
                stage_wnn_bf16(bH + boff, ldb, Bs, kp2, n8, 0);
            } else {
                stage_wnn_f32 (bF + boff, ldb, Bs, kp2, n8);
            }
        }
        __syncthreads();

        s16x8 aHi[4], aLo[4];
#pragma unroll
        for (int i = 0; i < 4; i++)
            aHi[i] = *(const s16x8*)((const char*)As + aoffH[i]);
        if (aHasLo) {
#pragma unroll
            for (int i = 0; i < 4; i++)
                aLo[i] = *(const s16x8*)((const char*)As + aoffL[i]);
        }

#pragma unroll
        for (int j = 0; j < 4; j++) {
            s16x8 bHi = *(const s16x8*)((const char*)Bs + boffH[j]);
#pragma unroll
            for (int i = 0; i < 4; i++)
                acc[i][j] = __builtin_amdgcn_mfma_f32_16x16x32_bf16(
                    aHi[i], bHi, acc[i][j], 0, 0, 0);
            if (bHasLo) {
                s16x8 bLo = *(const s16x8*)((const char*)Bs + boffL[j]);
#pragma unroll
                for (int i = 0; i < 4; i++)
                    acc[i][j] = __builtin_amdgcn_mfma_f32_16x16x32_bf16(
                        aHi[i], bLo, acc[i][j], 0, 0, 0);
            }
            if (aHasLo) {
#pragma unroll
                for (int i = 0; i < 4; i++)
                    acc[i][j] = __builtin_amdgcn_mfma_f32_16x16x32_bf16(
                        aLo[i], bHi, acc[i][j], 0, 0, 0);
            }
        }
    }

    // epilogue: C/D layout col=lane&15, row=(lane>>4)*4+reg
#pragma unroll
    for (int j = 0; j < 4; j++) {
        int col = n0 + wc * 64 + j * 16 + lr;
        float bv = 0.f;
        if (hasb) bv = bf ? bf2f(biasH[col]) : biasF[col];
#pragma unroll
        for (int i = 0; i < 4; i++) {
#pragma unroll
            for (int rr = 0; rr < 4; rr++) {
                int grow = m0 + wr * 64 + i * 16 + kg * 4 + rr;
                if (GATHER && grow >= Meff) continue;
                int crow = GATHER ? gl[grow] : grow;
                float v = acc[i][j][rr] + bv;
                if (RELU) v = fmaxf(v, 0.f);
                if (SCALE) v *= scalev[crow];
                if (OUTP) {
                    bf16_t hh, ll;
                    split_rne(v, hh, ll);
                    long off = (long)crow * ldc + col;
                    CpH[off] = hh;
                    CpH[cplane + off] = ll;
                } else {
                    Cp[(long)crow * ldc + col] = v;
                }
            }
        }
    }
}

// ---------------- generic wrapper -------------------------------------------
template<bool NT, bool RELU, bool GATHER, bool SCALE,
         bool MASK_TRI, bool MASK_K, bool SPLITK, bool OUTP>
__global__ __launch_bounds__(256, 2)
void mgemm_kernel(int amode, int bmode,
                  const void* a32, const void* a16, const void* a16lo,
                  const void* b32, const void* b16, const void* b16lo,
                  const void* bias32, const void* bias16,
                  float* C, void* CH, long cplane,
                  int M, int N, int K, int lda, int ldb, int ldc,
                  long aZ, long bZ, long biasZ, long cZ,
                  const int* __restrict__ glist, const int* __restrict__ counts,
                  const float* __restrict__ scalev,
                  const int* __restrict__ dtf)
{
    if (MASK_TRI && blockIdx.x > blockIdx.y) return;
    const int e  = SPLITK ? 0 : blockIdx.z;
    const int n0 = blockIdx.x * 128, m0 = blockIdx.y * 128;
    int Meff = M;
    const int* gl = nullptr;
    if (GATHER) {
        gl = glist + e * 4096;
        Meff = counts[e];
        if (m0 >= Meff) return;          // whole-block uniform, before barriers
    }
    const bool bf = (*dtf != 0);
    const int am = (amode < 0) ? (bf ? 1 : 0) : amode;
    const int bm = (bmode < 0) ? (bf ? 1 : 0) : bmode;

    const float*  aF = (const float*)a32 + (long)e * aZ;
    const bf16_t* aH = (const bf16_t*)a16 + (long)e * aZ;
    const bf16_t* aL = (const bf16_t*)a16lo + (long)e * aZ;
    const long bOff  = SPLITK ? 0 : (long)e * bZ;
    const float*  bF = (const float*)b32 + bOff;
    const bf16_t* bH = (const bf16_t*)b16 + bOff;
    const bf16_t* bL = (const bf16_t*)b16lo + bOff;

    float* Cp = nullptr;
    bf16_t* CpH = nullptr;
    int kBeg = 0, kEnd = K;
    if (SPLITK) {
        const int kc  = blockIdx.z;
        const int kch = (int)bZ;          // bZ reused as K-chunk size
        kBeg = kc * kch;
        kEnd = kBeg + kch;
        Cp = C + (long)kc * cZ;           // cZ = partial-plane stride
    } else {
        if (C)  Cp  = C + (long)e * cZ;
        if (CH) CpH = (bf16_t*)CH + (long)e * cZ;
        if (MASK_K) kEnd = (blockIdx.y + 1) * 128;
    }
    const bool hasb = !SPLITK && ((bias32 != nullptr) || (bias16 != nullptr));
    const float*  biasF = (const float*)bias32 + (long)e * biasZ;
    const bf16_t* biasH = (const bf16_t*)bias16 + (long)e * biasZ;

    mgemm_body<NT, RELU, GATHER, SCALE, OUTP>(am, aF, aH, aL, bm, bF, bH, bL,
        biasF, biasH, bf, hasb, Cp, CpH, cplane, lda, ldb, ldc, Meff, gl,
        scalev, kBeg, kEnd, m0, n0);
}

// ---------------- fused Q/K/V wrapper ---------------------------------------
struct TriArgs {
    const void* aF[3]; const void* aH[3]; const void* aL[3];
    const void* w32[3]; const void* w16[3];
    const void* b32[3]; const void* b16[3];
    void* dstH[3];
    int am[3];          // -1 = input dtype, 2 = ws pair
};

__global__ __launch_bounds__(256, 2)
void mgemm_tri_kernel(TriArgs ta, const int* __restrict__ dtf)
{
    const int z = blockIdx.z;
    const bool bf = (*dtf != 0);
    const int am = (ta.am[z] < 0) ? (bf ? 1 : 0) : ta.am[z];
    const int bm = bf ? 1 : 0;
    mgemm_body<false, false, false, false, true>(
        am, (const float*)ta.aF[z], (const bf16_t*)ta.aH[z], (const bf16_t*)ta.aL[z],
        bm, (const float*)ta.w32[z], (const bf16_t*)ta.w16[z], nullptr,
        (const float*)ta.b32[z], (const bf16_t*)ta.b16[z],
        bf, true,
        nullptr, (bf16_t*)ta.dstH[z], 4194304L,
        512, 4096, 4096,
        0, nullptr, nullptr,
        0, 512, blockIdx.y * 128, blockIdx.x * 128);
}

// ---------------- split-K reduce (+bias) ------------------------------------
template<int NCH>
__global__ __launch_bounds__(256)
void reduce_kernel(const float* __restrict__ part,
                   const void* bias32, const void* bias16,
                   float* __restrict__ out, const int* __restrict__ dtf)
{
    const bool bf = (*dtf != 0);
    const int i = (blockIdx.x * 256 + threadIdx.x) * 4;   // over 1024*512
    float4 s = *(const float4*)(part + i);
#pragma unroll
    for (int c = 1; c < NCH; c++) {
        float4 p = *(const float4*)(part + (long)c * 524288 + i);
        s.x += p.x; s.y += p.y; s.z += p.z; s.w += p.w;
    }
    const int col = i & 511;
    float b0, b1, b2, b3;
    if (bf) {
        const bf16_t* bb = (const bf16_t*)bias16;
        b0 = bf2f(bb[col]); b1 = bf2f(bb[col + 1]);
        b2 = bf2f(bb[col + 2]); b3 = bf2f(bb[col + 3]);
    } else {
        const float* bb = (const float*)bias32;
        b0 = bb[col]; b1 = bb[col + 1]; b2 = bb[col + 2]; b3 = bb[col + 3];
    }
    out[i + 0] = s.x + b0; out[i + 1] = s.y + b1;
    out[i + 2] = s.z + b2; out[i + 3] = s.w + b3;
}

// ---------------- Attention phase 2: softmax fp32 -> bf16 pair (in place) ---
// Row layout after this kernel: 4KB row = [hi bf16 x1024 | lo bf16 x1024].
template<bool MASKED>
__global__ __launch_bounds__(256)
void softmax_kernel(float* __restrict__ sb)
{
    const int g = blockIdx.x * 4 + (threadIdx.x >> 6);
    const int lane = threadIdx.x & 63;
    const int r = g & 1023;
    float* row = sb + (long)g * 1024;
    bf16_t* rowh = (bf16_t*)row;
    const int n = MASKED ? (r + 1) : 1024;

    float vv[16];
    float m = -1e30f;
#pragma unroll
    for (int j = 0; j < 4; j++) {
        float4 v4 = *(const float4*)(row + j * 256 + lane * 4);
        const float* pv = (const float*)&v4;
#pragma unroll
        for (int c = 0; c < 4; c++) {
            int idx = j * 256 + lane * 4 + c;
            float x = (idx < n) ? pv[c] : -1e30f;
            vv[j * 4 + c] = x;
            m = fmaxf(m, x);
        }
    }
    m = waveReduceMax(m);
    float sum = 0.0f;
#pragma unroll
    for (int i = 0; i < 16; i++) {
        vv[i] = __expf(vv[i] - m);
        sum += vv[i];
    }
    sum = waveReduceSum(sum);
    float inv = 1.0f / sum;
#pragma unroll
    for (int j = 0; j < 4; j++) {
        ushort4 hh, ll;
        float p0 = vv[j * 4 + 0] * inv, p1 = vv[j * 4 + 1] * inv;
        float p2 = vv[j * 4 + 2] * inv, p3 = vv[j * 4 + 3] * inv;
        bf16_t h, l;
        split_rne(p0, h, l); hh.x = h; ll.x = l;
        split_rne(p1, h, l); hh.y = h; ll.y = l;
        split_rne(p2, h, l); hh.z = h; ll.z = l;
        split_rne(p3, h, l); hh.w = h; ll.w = l;
        *(ushort4*)(rowh + (j * 256 + lane * 4)) = hh;
        *(ushort4*)(rowh + 1024 + (j * 256 + lane * 4)) = ll;
    }
}

// ---------------- Fallback flash (small-ws path) ----------------------------
template<bool MASKED>
__global__ __launch_bounds__(256)
void flash_kernel(const bf16_t* __restrict__ qh, const bf16_t* __restrict__ ql,
                  const bf16_t* __restrict__ kh, const bf16_t* __restrict__ kl,
                  const bf16_t* __restrict__ vh, const bf16_t* __restrict__ vl,
                  bf16_t* __restrict__ outH)
{
    const int h = blockIdx.y;
    const long bh = (long)h * 524288L;
    const int t = threadIdx.x, lane = t & 63, wave = t >> 6;
    const int base = blockIdx.x * 32;
    const int row0 = base + wave * 8;

    float qreg[8][8], oacc[8][8];
    float mi[8], li[8];
#pragma unroll
    for (int i = 0; i < 8; i++) {
        mi[i] = -1e30f;
        li[i] = 0.0f;
#pragma unroll
        for (int d = 0; d < 8; d++) {
            long idx = bh + (long)(row0 + i) * 512 + lane + 64 * d;
            qreg[i][d] = bf2f(qh[idx]) + bf2f(ql[idx]);
            oacc[i][d] = 0.0f;
        }
    }

    __shared__ float ks[8][512];
    __shared__ float vs[8][512];

    const int kmax = MASKED ? (base + 31) : 1023;
    for (int k0 = 0; k0 <= kmax; k0 += 8) {
        __syncthreads();
#pragma unroll
        for (int r = 0; r < 4; r++) {
            int flat = (r * 256 + t) * 4;
            int kr = flat >> 9, col = flat & 511;
            long idx = bh + (long)(k0 + kr) * 512 + col;
            ushort4 kh4 = *(const ushort4*)&kh[idx];
            ushort4 kl4 = *(const ushort4*)&kl[idx];
            ushort4 vh4 = *(const ushort4*)&vh[idx];
            ushort4 vl4 = *(const ushort4*)&vl[idx];
            ks[kr][col + 0] = bf2f(kh4.x) + bf2f(kl4.x);
            ks[kr][col + 1] = bf2f(kh4.y) + bf2f(kl4.y);
            ks[kr][col + 2] = bf2f(kh4.z) + bf2f(kl4.z);
            ks[kr][col + 3] = bf2f(kh4.w) + bf2f(kl4.w);
            vs[kr][col + 0] = bf2f(vh4.x) + bf2f(vl4.x);
            vs[kr][col + 1] = bf2f(vh4.y) + bf2f(vl4.y);
            vs[kr][col + 2] = bf2f(vh4.z) + bf2f(vl4.z);
            vs[kr][col + 3] = bf2f(vh4.w) + bf2f(vl4.w);
        }
        __syncthreads();
#pragma unroll
        for (int j = 0; j < 8; j++) {
            const int kg = k0 + j;
#pragma unroll
            for (int i = 0; i < 8; i++) {
                const int qrow = row0 + i;
                if (MASKED && kg > qrow) continue;
                float p = 0.0f;
#pragma unroll
                for (int d = 0; d < 8; d++)
                    p = fmaf(qreg[i][d], ks[j][lane + 64 * d], p);
                p = waveReduceSum(p);
                float mnew = fmaxf(mi[i], p);
                float sc = __expf(mi[i] - mnew);
                float pe = __expf(p - mnew);
                li[i] = li[i] * sc + pe;
                mi[i] = mnew;
#pragma unroll
                for (int d = 0; d < 8; d++)
                    oacc[i][d] = fmaf(oacc[i][d], sc, pe * vs[j][lane + 64 * d]);
            }
        }
    }

#pragma unroll
    for (int i = 0; i < 8; i++) {
        float inv = 1.0f / li[i];
#pragma unroll
        for (int d = 0; d < 8; d++) {
            long off = (long)(row0 + i) * 4096 + h * 512 + lane + 64 * d;
            bf16_t hh, ll;
            split_rne(oacc[i][d] * inv, hh, ll);
            outH[off] = hh;
            outH[4194304L + off] = ll;
        }
    }
}

// ---------------- Fused residual add + LayerNorm ----------------------------
// RM: 0 = residual in model dtype, 1 = residual is ws bf16 pair.
// OM: 0 = output in model dtype, 1 = output is ws bf16 pair.
template<int RM, int OM>
__global__ __launch_bounds__(256)
void add_ln_kernel(const float* __restrict__ a,
                   const void* r32, const void* r16, const void* r16lo,
                   const void* g32, const void* g16,
                   const void* b32, const void* b16,
                   void* out, void* outLo, const int* __restrict__ dtf)
{
    const bool bf = (*dtf != 0);
    const int row = blockIdx.x, t = threadIdx.x;
    const long o = (long)row * 512;

    float r0, r1;
    if (RM == 1) {
        const bf16_t* rh = (const bf16_t*)r16;
        const bf16_t* rl = (const bf16_t*)r16lo;
        r0 = bf2f(rh[o + t]) + bf2f(rl[o + t]);
        r1 = bf2f(rh[o + 256 + t]) + bf2f(rl[o + 256 + t]);
    } else if (bf) {
        r0 = bf2f(((const bf16_t*)r16)[o + t]);
        r1 = bf2f(((const bf16_t*)r16)[o + 256 + t]);
    } else {
        r0 = ((const float*)r32)[o + t];
        r1 = ((const float*)r32)[o + 256 + t];
    }
    float z0 = a[o + t] + r0;
    float z1 = a[o + 256 + t] + r1;

    __shared__ float red[4];
    const int lane = t & 63, wave = t >> 6;

    float s = waveReduceSum(z0 + z1);
    if (lane == 0) red[wave] = s;
    __syncthreads();
    float mean = (red[0] + red[1] + red[2] + red[3]) * (1.0f / 512.0f);
    float d0 = z0 - mean, d1 = z1 - mean;
    float vsum = waveReduceSum(d0 * d0 + d1 * d1);
    __syncthreads();
    if (lane == 0) red[wave] = vsum;
    __syncthreads();
    float var = (red[0] + red[1] + red[2] + red[3]) * (1.0f / 512.0f);
    float rstd = rsqrtf(var + 1e-5f);

    float gg0, gg1, bb0, bb1;
    if (bf) {
        gg0 = bf2f(((const bf16_t*)g16)[t]);  gg1 = bf2f(((const bf16_t*)g16)[t + 256]);
        bb0 = bf2f(((const bf16_t*)b16)[t]);  bb1 = bf2f(((const bf16_t*)b16)[t + 256]);
    } else {
        gg0 = ((const float*)g32)[t];         gg1 = ((const float*)g32)[t + 256];
        bb0 = ((const float*)b32)[t];         bb1 = ((const float*)b32)[t + 256];
    }
    float o0 = gg0 * d0 * rstd + bb0;
    float o1 = gg1 * d1 * rstd + bb1;
    if (OM == 1) {
        bf16_t* oh = (bf16_t*)out;
        bf16_t* ol = (bf16_t*)outLo;
        bf16_t hh, ll;
        split_rne(o0, hh, ll); oh[o + t] = hh;        ol[o + t] = ll;
        split_rne(o1, hh, ll); oh[o + 256 + t] = hh;  ol[o + 256 + t] = ll;
    } else if (bf) {
        ((bf16_t*)out)[o + t] = f2bf(o0);
        ((bf16_t*)out)[o + 256 + t] = f2bf(o1);
    } else {
        ((float*)out)[o + t] = o0;
        ((float*)out)[o + 256 + t] = o1;
    }
}

// ---------------- Gating (x is bf16 pair) -----------------------------------
__global__ __launch_bounds__(256)
void gate_kernel(const bf16_t* __restrict__ xh, const bf16_t* __restrict__ xl,
                 const void* gw32, const void* gw16,
                 const void* gb32, const void* gb16,
                 int* __restrict__ sel, float* __restrict__ wsel,
                 const int* __restrict__ dtf)
{
    const bool bf = (*dtf != 0);
    const int lane = threadIdx.x & 63, wave = threadIdx.x >> 6;
    const int token = blockIdx.x * 4 + wave;
    float xr[8];
#pragma unroll
    for (int i = 0; i < 8; i++) {
        long idx = (long)token * 512 + lane + 64 * i;
        xr[i] = bf2f(xh[idx]) + bf2f(xl[idx]);
    }
    float logits[8];
#pragma unroll
    for (int e = 0; e < 8; e++) {
        float p = 0.0f;
#pragma unroll
        for (int i = 0; i < 8; i++) {
            long idx = (long)(lane + 64 * i) * 8 + e;
            float w = bf ? bf2f(((const bf16_t*)gw16)[idx]) : ((const float*)gw32)[idx];
            p = fmaf(xr[i], w, p);
        }
        p = waveReduceSum(p);
        float b = bf ? bf2f(((const bf16_t*)gb16)[e]) : ((const float*)gb32)[e];
        logits[e] = p + b;
    }
    if (lane == 0) {
        float m1 = -1e30f, m2 = -1e30f;
        int i1 = 0, i2 = 0;
#pragma unroll
        for (int e = 0; e < 8; e++) {
            float vv = logits[e];
            if (vv > m1) { m2 = m1; i2 = i1; m1 = vv; i1 = e; }
            else if (vv > m2) { m2 = vv; i2 = e; }
        }
        float ed = __expf(m2 - m1);
        sel[token]  = i2;
        wsel[token] = ed / (1.0f + ed);
    }
}

__global__ void zero_counts_kernel(int* __restrict__ counts)
{
    if (threadIdx.x < 8) counts[threadIdx.x] = 0;
}

__global__ __launch_bounds__(256)
void route_kernel(const int* __restrict__ sel, int* __restrict__ counts,
                  int* __restrict__ idx)
{
    int tk = blockIdx.x * 256 + threadIdx.x;
    int e = sel[tk] & 7;
    int pos = atomicAdd(&counts[e], 1) & 4095;
    idx[e * 4096 + pos] = tk;
}

// ---------------------------------------------------------------------------
extern "C" void kernel_launch(void* const* d_in, const int* in_sizes, int n_in,
                              void* d_out, int out_size, void* d_ws, size_t ws_size,
                              hipStream_t stream)
{
    const char* x_in = (const char*)d_in[0];
    const char* enc  = (const char*)d_in[1];
    const char* wq   = (const char*)d_in[2];
    const char* bq   = (const char*)d_in[3];
    const char* wk   = (const char*)d_in[4];
    const char* bk   = (const char*)d_in[5];
    const char* wv   = (const char*)d_in[6];
    const char* bv   = (const char*)d_in[7];
    const char* wo   = (const char*)d_in[8];
    const char* bo   = (const char*)d_in[9];
    const char* gw   = (const char*)d_in[10];
    const char* gb   = (const char*)d_in[11];
    const char* ew1  = (const char*)d_in[12];
    const char* eb1  = (const char*)d_in[13];
    const char* ew2  = (const char*)d_in[14];
    const char* eb2  = (const char*)d_in[15];
    const char* lng  = (const char*)d_in[16];
    const char* lnb  = (const char*)d_in[17];

    float* ws = (float*)d_ws;
    const long SZ_X = 4096L * 512;
    const long SZ_B = 1024L * 4096;
    float* xb = ws;
    float* ab = xb + SZ_X;
    float* qb = ab + SZ_X;
    float* kb = qb + SZ_B;
    float* vb = kb + SZ_B;
    float* cb = vb + SZ_B;
    float* h1 = qb;                  // aliases qb (dead during MoE)
    float* yb = kb;                  // aliases kb (dead during MoE)
    float* wselp = cb + SZ_B;
    int* selp   = (int*)(wselp + 4096);
    int* counts = selp + 4096;
    int* idxl   = counts + 8;
    int* dtf    = idxl + 8 * 4096;
    long sb_off = (((long)(dtf + 1 - (int*)ws)) + 3) & ~3L;
    float* sbuf = ws + sb_off;
    const long NEED = (sb_off + 8L * 1048576L) * 4L;   // bytes
    const bool big = (ws_size >= (size_t)NEED);

    // bf16 pair plane views (hi plane at base, lo plane at +plane elements)
    bf16_t* xh  = (bf16_t*)xb;   bf16_t* xl  = xh + 2097152;   // [4096,512]
    bf16_t* qh  = (bf16_t*)qb;   bf16_t* ql  = qh + 4194304;   // [1024,4096]
    bf16_t* kh  = (bf16_t*)kb;   bf16_t* kl  = kh + 4194304;
    bf16_t* vh  = (bf16_t*)vb;   bf16_t* vl  = vh + 4194304;
    bf16_t* cbh = (bf16_t*)cb;   bf16_t* cbl = cbh + 4194304;
    bf16_t* h1h = (bf16_t*)h1;   bf16_t* h1l = h1h + 4194304;  // [4096,1024]
    bf16_t* sbh = (bf16_t*)sbuf;                               // pair-per-row

    dim3 blk(256);
    const long SB = 1024L * 512;     // per-batch elements of x/enc
    const long L3 = 512L * 4096;     // per-(l,att) elements of wq/wk/wv
    const long LO = 4096L * 512;     // per-(l,att) elements of wo

    probe_kernel<<<1, 64, 0, stream>>>((const unsigned int*)lng, dtf);

    const char* cur = x_in;
    bool cur_is_ws = false;

    for (int l = 0; l < 2; l++) {
        for (int att = 0; att < 2; att++) {
            const long woff = (long)(l * 2 + att);
            const void* Wx32[4] = { wq + woff * L3 * 4, wk + woff * L3 * 4,
                                    wv + woff * L3 * 4, wo + woff * LO * 4 };
            const void* Wx16[4] = { wq + woff * L3 * 2, wk + woff * L3 * 2,
                                    wv + woff * L3 * 2, wo + woff * LO * 2 };
            const void* Bx32[4] = { bq + woff * 4096 * 4, bk + woff * 4096 * 4,
                                    bv + woff * 4096 * 4, bo + woff * 512 * 4 };
            const void* Bx16[4] = { bq + woff * 4096 * 2, bk + woff * 4096 * 2,
                                    bv + woff * 4096 * 2, bo + woff * 512 * 2 };

            for (int b = 0; b < 4; b++) {
                const bool aqk_in = (att == 1) || !cur_is_ws;
                void* dst3[3] = { qb, kb, vb };

                TriArgs ta;
                for (int m = 0; m < 3; m++) {
                    const bool a_in = (m == 2) ? !cur_is_ws : aqk_in;
                    if (a_in) {
                        const char* Asrc = (m == 2) ? x_in : ((att == 1) ? enc : x_in);
                        ta.am[m] = -1;
                        ta.aF[m] = Asrc + b * SB * 4;
                        ta.aH[m] = Asrc + b * SB * 2;
                        ta.aL[m] = nullptr;
                    } else {
                        ta.am[m] = 2;
                        ta.aF[m] = nullptr;
                        ta.aH[m] = xh + b * SB;
                        ta.aL[m] = xl + b * SB;
                    }
                    ta.w32[m] = Wx32[m]; ta.w16[m] = Wx16[m];
                    ta.b32[m] = Bx32[m]; ta.b16[m] = Bx16[m];
                    ta.dstH[m] = dst3[m];
                }
                mgemm_tri_kernel<<<dim3(32, 8, 3), blk, 0, stream>>>(ta, dtf);

                if (big) {
                    if (att == 0) {
                        mgemm_kernel<true, false, false, false, true, false, false, false>
                            <<<dim3(8, 8, 8), blk, 0, stream>>>(
                            2, 2, nullptr, qh, ql, nullptr, kh, kl,
                            nullptr, nullptr, sbuf, nullptr, 0,
                            1024, 1024, 512, 512, 512, 1024,
                            524288L, 524288L, 0, 1048576L,
                            nullptr, nullptr, nullptr, dtf);
                        softmax_kernel<true><<<2048, blk, 0, stream>>>(sbuf);
                        mgemm_kernel<false, false, false, false, false, true, false, true>
                            <<<dim3(4, 8, 8), blk, 0, stream>>>(
                            2, 2, nullptr, sbh, sbh + 1024, nullptr, vh, vl,
                            nullptr, nullptr, nullptr, cbh, 4194304L,
                            1024, 512, 1024, 2048, 512, 4096,
                            2097152L, 524288L, 0, 512L,
                            nullptr, nullptr, nullptr, dtf);
                    } else {
                        mgemm_kernel<true, false, false, false, false, false, false, false>
                            <<<dim3(8, 8, 8), blk, 0, stream>>>(
                            2, 2, nullptr, qh, ql, nullptr, kh, kl,
                            nullptr, nullptr, sbuf, nullptr, 0,
                            1024, 1024, 512, 512, 512, 1024,
                            524288L, 524288L, 0, 1048576L,
                            nullptr, nullptr, nullptr, dtf);
                        softmax_kernel<false><<<2048, blk, 0, stream>>>(sbuf);
                        mgemm_kernel<false, false, false, false, false, false, false, true>
                            <<<dim3(4, 8, 8), blk, 0, stream>>>(
                            2, 2, nullptr, sbh, sbh + 1024, nullptr, vh, vl,
                            nullptr, nullptr, nullptr, cbh, 4194304L,
                            1024, 512, 1024, 2048, 512, 4096,
                            2097152L, 524288L, 0, 512L,
                            nullptr, nullptr, nullptr, dtf);
                    }
                    // out-proj split-K: 16 chunks of K=256 -> partials in sbuf
                    mgemm_kernel<false, false, false, false, false, false, true, false>
                        <<<dim3(4, 8, 16), blk, 0, stream>>>(
                        2, -1, nullptr, cbh, cbl, Wx32[3], Wx16[3], nullptr,
                        nullptr, nullptr, sbuf, nullptr, 0,
                        1024, 512, 4096, 4096, 512, 512,
                        0, 256 /*K-chunk*/, 0, 524288L /*plane stride*/,
                        nullptr, nullptr, nullptr, dtf);
                    reduce_kernel<16><<<512, blk, 0, stream>>>(
                        sbuf, Bx32[3], Bx16[3], ab + b * SB, dtf);
                } else {
                    if (att == 0)
                        flash_kernel<true><<<dim3(32, 8), blk, 0, stream>>>(
                            qh, ql, kh, kl, vh, vl, cbh);
                    else
                        flash_kernel<false><<<dim3(32, 8), blk, 0, stream>>>(
                            qh, ql, kh, kl, vh, vl, cbh);
                    mgemm_kernel<false, false, false, false, false, false, false, false>
                        <<<dim3(4, 8, 1), blk, 0, stream>>>(
                        2, -1, nullptr, cbh, cbl, Wx32[3], Wx16[3], nullptr,
                        Bx32[3], Bx16[3], ab + b * SB, nullptr, 0,
                        1024, 512, 4096, 4096, 512, 512,
                        0, 0, 0, 0, nullptr, nullptr, nullptr, dtf);
                }
            }

            const void* G32  = lng + (long)(l * 3 + att) * 512 * 4;
            const void* G16  = lng + (long)(l * 3 + att) * 512 * 2;
            const void* Bt32 = lnb + (long)(l * 3 + att) * 512 * 4;
            const void* Bt16 = lnb + (long)(l * 3 + att) * 512 * 2;
            if (cur_is_ws)
                add_ln_kernel<1, 1><<<4096, blk, 0, stream>>>(
                    ab, nullptr, xh, xl, G32, G16, Bt32, Bt16, xh, xl, dtf);
            else
                add_ln_kernel<0, 1><<<4096, blk, 0, stream>>>(
                    ab, (const void*)cur, (const void*)cur, nullptr,
                    G32, G16, Bt32, Bt16, xh, xl, dtf);
            cur = (const char*)xb; cur_is_ws = true;
        }

        // ---- MoE ----
        gate_kernel<<<1024, blk, 0, stream>>>(
            xh, xl, gw + (long)l * 512 * 8 * 4, gw + (long)l * 512 * 8 * 2,
            gb + (long)l * 8 * 4, gb + (long)l * 8 * 2, selp, wselp, dtf);
        zero_counts_kernel<<<1, 64, 0, stream>>>(counts);
        route_kernel<<<16, blk, 0, stream>>>(selp, counts, idxl);

        mgemm_kernel<false, true, true, false, false, false, false, true>
            <<<dim3(8, 32, 8), blk, 0, stream>>>(
            2, -1, nullptr, xh, xl,
            ew1 + (long)l * 8 * 512 * 1024 * 4, ew1 + (long)l * 8 * 512 * 1024 * 2,
            nullptr,
            eb1 + (long)l * 8 * 1024 * 4, eb1 + (long)l * 8 * 1024 * 2,
            nullptr, h1h, 4194304L,
            4096, 1024, 512, 512, 1024, 1024,
            0, 512L * 1024, 1024, 0, idxl, counts, nullptr, dtf);
        mgemm_kernel<false, false, true, true, false, false, false, false>
            <<<dim3(4, 32, 8), blk, 0, stream>>>(
            2, -1, nullptr, h1h, h1l,
            ew2 + (long)l * 8 * 1024 * 512 * 4, ew2 + (long)l * 8 * 1024 * 512 * 2,
            nullptr,
            eb2 + (long)l * 8 * 512 * 4, eb2 + (long)l * 8 * 512 * 2,
            yb, nullptr, 0,
            4096, 512, 1024, 1024, 512, 512,
            0, 1024L * 512, 512, 0, idxl, counts, wselp, dtf);

        const void* G32  = lng + (long)(l * 3 + 2) * 512 * 4;
        const void* G16  = lng + (long)(l * 3 + 2) * 512 * 2;
        const void* Bt32 = lnb + (long)(l * 3 + 2) * 512 * 4;
        const void* Bt16 = lnb + (long)(l * 3 + 2) * 512 * 2;
        if (l == 0)
            add_ln_kernel<1, 1><<<4096, blk, 0, stream>>>(
                yb, nullptr, xh, xl, G32, G16, Bt32, Bt16, xh, xl, dtf);
        else
            add_ln_kernel<1, 0><<<4096, blk, 0, stream>>>(
                yb, nullptr, xh, xl, G32, G16, Bt32, Bt16, d_out, nullptr, dtf);
    }
}

// Round 6
// 3937.569 us; speedup vs baseline: 1.0907x; 1.0907x over previous
//
#include <hip/hip_runtime.h>
#include <math.h>

// ---------------------------------------------------------------------------
// Round N+4: register-prefetch software pipelining in mgemm_body.
// Post-mortem of N+3: pair storage = same 4B/elem as fp32 -> FETCH unchanged;
// kernels are LATENCY-bound (All pipes <6%, 543 GB/s = in-flight-limited).
// Fix: in the bf16/pair fast path, load tile k+1 into registers right after
// the compute barrier so HBM latency overlaps ds_read+MFMA of tile k.
// Same 2 barriers/iter; vmcnt wait lands at the next LDS write.
// fp32-mode GEMMs use the old single-buffered loop (fallback only).
// Everything else identical to round N+3 (absmax must stay 0.015625).
// ---------------------------------------------------------------------------

typedef unsigned short bf16_t;
typedef __attribute__((ext_vector_type(8))) short s16x8;
typedef __attribute__((ext_vector_type(8))) unsigned short u16x8;
typedef __attribute__((ext_vector_type(4))) float f32x4;

__device__ __forceinline__ float bf2f(bf16_t u) {
    union { unsigned int i; float f; } v; v.i = ((unsigned int)u) << 16; return v.f;
}
__device__ __forceinline__ bf16_t f2bf(float f) {
    union { float f; unsigned int i; } v; v.f = f;
    unsigned int x = v.i;
    return (bf16_t)((x + 0x7fffu + ((x >> 16) & 1u)) >> 16);  // RNE
}
// hi = truncated-to-bf16 part, rem = x - hi (exact in fp32)
__device__ __forceinline__ bf16_t bfhi_trunc(float x, float& rem) {
    union { float f; unsigned u; } v; v.f = x;
    unsigned hu = v.u & 0xFFFF0000u;
    union { unsigned u; float f; } h; h.u = hu;
    rem = x - h.f;
    return (bf16_t)(hu >> 16);
}
// RNE pair split: x ~= hi + lo to ~2^-18 relative
__device__ __forceinline__ void split_rne(float x, bf16_t& hi, bf16_t& lo) {
    bf16_t h = f2bf(x);
    float hf = bf2f(h);
    lo = f2bf(x - hf);
    hi = h;
}

__device__ __forceinline__ float waveReduceSum(float x) {
    x += __shfl_xor(x, 1);  x += __shfl_xor(x, 2);  x += __shfl_xor(x, 4);
    x += __shfl_xor(x, 8);  x += __shfl_xor(x, 16); x += __shfl_xor(x, 32);
    return x;
}
__device__ __forceinline__ float waveReduceMax(float x) {
    x = fmaxf(x, __shfl_xor(x, 1));  x = fmaxf(x, __shfl_xor(x, 2));
    x = fmaxf(x, __shfl_xor(x, 4));  x = fmaxf(x, __shfl_xor(x, 8));
    x = fmaxf(x, __shfl_xor(x, 16)); x = fmaxf(x, __shfl_xor(x, 32));
    return x;
}

// ---------------- dtype probe ----------------------------------------------
__global__ void probe_kernel(const unsigned int* __restrict__ lng_u32,
                             int* __restrict__ flag)
{
    if (threadIdx.x == 0 && blockIdx.x == 0)
        *flag = (lng_u32[0] == 0x3F803F80u) ? 1 : 0;
}

// ---------------- LDS staging helpers (slow/f32 path only) ------------------
// LDS tile row = 128 bytes: [hi bf16 k=0..31 | lo bf16 k=0..31], swizzled by
// byte ^= ((row&7)<<4). Writes and reads use the same bijection.

__device__ __forceinline__ void stage_f32_row(const float* __restrict__ src,
                                              char* rowp, int h, int r)
{
    float xx[16];
    *(float4*)(xx + 0)  = *(const float4*)(src + 0);
    *(float4*)(xx + 4)  = *(const float4*)(src + 4);
    *(float4*)(xx + 8)  = *(const float4*)(src + 8);
    *(float4*)(xx + 12) = *(const float4*)(src + 12);
    u16x8 h0, h1, l0, l1;
#pragma unroll
    for (int i = 0; i < 8; i++) {
        float r0, r1;
        h0[i] = bfhi_trunc(xx[i], r0);      l0[i] = f2bf(r0);
        h1[i] = bfhi_trunc(xx[8 + i], r1);  l1[i] = f2bf(r1);
    }
    const int sw = (r & 7) << 4;
    *(u16x8*)(rowp + ((32 * h + 0)  ^ sw)) = h0;
    *(u16x8*)(rowp + ((32 * h + 16) ^ sw)) = h1;
    *(u16x8*)(rowp + ((64 + 32 * h + 0)  ^ sw)) = l0;
    *(u16x8*)(rowp + ((64 + 32 * h + 16) ^ sw)) = l1;
}

__device__ __forceinline__ void stage_bf16_row(const bf16_t* __restrict__ src,
                                               char* rowp, int h, int r)
{
    u16x8 v0 = *(const u16x8*)(src);
    u16x8 v1 = *(const u16x8*)(src + 8);
    const int sw = (r & 7) << 4;
    *(u16x8*)(rowp + ((32 * h + 0)  ^ sw)) = v0;
    *(u16x8*)(rowp + ((32 * h + 16) ^ sw)) = v1;
}

__device__ __forceinline__ void stage_pair_row(const bf16_t* __restrict__ hi,
                                               const bf16_t* __restrict__ lo,
                                               char* rowp, int h, int r)
{
    u16x8 h0 = *(const u16x8*)(hi);
    u16x8 h1 = *(const u16x8*)(hi + 8);
    u16x8 l0 = *(const u16x8*)(lo);
    u16x8 l1 = *(const u16x8*)(lo + 8);
    const int sw = (r & 7) << 4;
    *(u16x8*)(rowp + ((32 * h + 0)  ^ sw)) = h0;
    *(u16x8*)(rowp + ((32 * h + 16) ^ sw)) = h1;
    *(u16x8*)(rowp + ((64 + 32 * h + 0)  ^ sw)) = l0;
    *(u16x8*)(rowp + ((64 + 32 * h + 16) ^ sw)) = l1;
}

__device__ __forceinline__ void stage_wnn_f32(const float* __restrict__ src,
                                              int ldb, ushort (*Bs)[64],
                                              int kp2, int n8)
{
    float a0[8], a1[8];
    *(float4*)(a0 + 0) = *(const float4*)(src);
    *(float4*)(a0 + 4) = *(const float4*)(src + 4);
    *(float4*)(a1 + 0) = *(const float4*)(src + ldb);
    *(float4*)(a1 + 4) = *(const float4*)(src + ldb + 4);
#pragma unroll
    for (int j = 0; j < 8; j++) {
        int rr = n8 + j;
        float q0, q1;
        bf16_t h0 = bfhi_trunc(a0[j], q0);
        bf16_t h1 = bfhi_trunc(a1[j], q1);
        unsigned vh = (unsigned)h0 | ((unsigned)h1 << 16);
        unsigned vl = (unsigned)f2bf(q0) | ((unsigned)f2bf(q1) << 16);
        char* rp = (char*)&Bs[rr][0];
        int sw = (rr & 7) << 4;
        *(unsigned*)(rp + ((2 * kp2) ^ sw)) = vh;
        *(unsigned*)(rp + ((64 + 2 * kp2) ^ sw)) = vl;
    }
}

__device__ __forceinline__ void stage_wnn_bf16(const bf16_t* __restrict__ src,
                                               int ldb, ushort (*Bs)[64],
                                               int kp2, int n8, int base)
{
    u16x8 r0 = *(const u16x8*)(src);
    u16x8 r1 = *(const u16x8*)(src + ldb);
#pragma unroll
    for (int j = 0; j < 8; j++) {
        int rr = n8 + j;
        unsigned v = (unsigned)(unsigned short)r0[j] |
                     ((unsigned)(unsigned short)r1[j] << 16);
        *(unsigned*)((char*)&Bs[rr][0] + ((base + 2 * kp2) ^ ((rr & 7) << 4))) = v;
    }
}

// ---------------- Unified MFMA GEMM body ------------------------------------
// am/bm: 0 = fp32 (split at stage), 1 = bf16 single (exact), 2 = bf16 pair.
template<bool NT, bool RELU, bool GATHER, bool SCALE, bool OUTP>
__device__ __forceinline__
void mgemm_body(int am, const float* __restrict__ aF,
                const bf16_t* __restrict__ aH, const bf16_t* __restrict__ aL,
                int bm, const float* __restrict__ bF,
                const bf16_t* __restrict__ bH, const bf16_t* __restrict__ bL,
                const float* __restrict__ biasF, const bf16_t* __restrict__ biasH,
                const bool bf, const bool hasb,
                float* __restrict__ Cp, bf16_t* __restrict__ CpH, long cplane,
                int lda, int ldb, int ldc,
                int Meff, const int* __restrict__ gl,
                const float* __restrict__ scalev,
                int kBeg, int kEnd, int m0, int n0)
{
    __shared__ __align__(16) ushort As[128][64];
    __shared__ __align__(16) ushort Bs[128][64];

    const int t   = threadIdx.x;
    const int sr  = t >> 1;               // staging row 0..127
    const int sh  = t & 1;                // k-half
    const int kp2 = (t & 15) * 2;         // NN staging k-pair
    const int n8  = (t >> 4) * 8;         // NN staging n-chunk

    int agr = m0 + sr;
    if (GATHER) agr = gl[(m0 + sr < Meff) ? (m0 + sr) : (Meff - 1)];

    const int lane = t & 63;
    const int wv = t >> 6;
    const int wr = wv >> 1, wc = wv & 1;
    const int lr = lane & 15, kg = lane >> 4;

    int aoffH[4], aoffL[4], boffH[4], boffL[4];
#pragma unroll
    for (int i = 0; i < 4; i++) {
        int ra = wr * 64 + i * 16 + lr;
        int sa = (ra & 7) << 4;
        aoffH[i] = ra * 128 + ((kg * 16) ^ sa);
        aoffL[i] = ra * 128 + ((64 + kg * 16) ^ sa);
        int rb = wc * 64 + i * 16 + lr;
        int sb = (rb & 7) << 4;
        boffH[i] = rb * 128 + ((kg * 16) ^ sb);
        boffL[i] = rb * 128 + ((64 + kg * 16) ^ sb);
    }

    f32x4 acc[4][4];
#pragma unroll
    for (int i = 0; i < 4; i++)
#pragma unroll
        for (int j = 0; j < 4; j++)
            acc[i][j] = (f32x4){0.f, 0.f, 0.f, 0.f};

    const bool aHasLo = (am != 1);
    const bool bHasLo = (bm != 1);

    if (am >= 1 && bm >= 1) {
        // ----- fast path: bf16/pair staging with register prefetch -----
        u16x8 pa0, pa1, pa2, pa3;
        u16x8 pb0, pb1, pb2, pb3;

        auto loadT = [&](int k0) {
            long aoff = (long)agr * lda + k0 + sh * 16;
            pa0 = *(const u16x8*)(aH + aoff);
            pa1 = *(const u16x8*)(aH + aoff + 8);
            if (am == 2) {
                pa2 = *(const u16x8*)(aL + aoff);
                pa3 = *(const u16x8*)(aL + aoff + 8);
            }
            if (NT) {
                long boff = (long)(n0 + sr) * ldb + k0 + sh * 16;
                pb0 = *(const u16x8*)(bH + boff);
                pb1 = *(const u16x8*)(bH + boff + 8);
                if (bm == 2) {
                    pb2 = *(const u16x8*)(bL + boff);
                    pb3 = *(const u16x8*)(bL + boff + 8);
                }
            } else {
                long boff = (long)(k0 + kp2) * ldb + n0 + n8;
                pb0 = *(const u16x8*)(bH + boff);
                pb1 = *(const u16x8*)(bH + boff + ldb);
                if (bm == 2) {
                    pb2 = *(const u16x8*)(bL + boff);
                    pb3 = *(const u16x8*)(bL + boff + ldb);
                }
            }
        };
        auto storeT = [&]() {
            const int swA = (sr & 7) << 4;
            char* rowpA = (char*)&As[sr][0];
            *(u16x8*)(rowpA + ((32 * sh + 0)  ^ swA)) = pa0;
            *(u16x8*)(rowpA + ((32 * sh + 16) ^ swA)) = pa1;
            if (am == 2) {
                *(u16x8*)(rowpA + ((64 + 32 * sh + 0)  ^ swA)) = pa2;
                *(u16x8*)(rowpA + ((64 + 32 * sh + 16) ^ swA)) = pa3;
            }
            if (NT) {
                char* rowpB = (char*)&Bs[sr][0];
                *(u16x8*)(rowpB + ((32 * sh + 0)  ^ swA)) = pb0;
                *(u16x8*)(rowpB + ((32 * sh + 16) ^ swA)) = pb1;
                if (bm == 2) {
                    *(u16x8*)(rowpB + ((64 + 32 * sh + 0)  ^ swA)) = pb2;
                    *(u16x8*)(rowpB + ((64 + 32 * sh + 16) ^ swA)) = pb3;
                }
            } else {
#pragma unroll
                for (int j = 0; j < 8; j++) {
                    int rr = n8 + j;
                    int sw = (rr & 7) << 4;
                    char* rp = (char*)&Bs[rr][0];
                    unsigned vh = (unsigned)(unsigned short)pb0[j] |
                                  ((unsigned)(unsigned short)pb1[j] << 16);
                    *(unsigned*)(rp + ((2 * kp2) ^ sw)) = vh;
                    if (bm == 2) {
                        unsigned vl = (unsigned)(unsigned short)pb2[j] |
                                      ((unsigned)(unsigned short)pb3[j] << 16);
                        *(unsigned*)(rp + ((64 + 2 * kp2) ^ sw)) = vl;
                    }
                }
            }
        };

        loadT(kBeg);
        for (int k0 = kBeg; k0 < kEnd; k0 += 32) {
            __syncthreads();
            storeT();                       // vmcnt wait lands here
            __syncthreads();
            if (k0 + 32 < kEnd) loadT(k0 + 32);   // overlap with ds_read+MFMA

            s16x8 aHi[4], aLo[4];
#pragma unroll
            for (int i = 0; i < 4; i++)
                aHi[i] = *(const s16x8*)((const char*)As + aoffH[i]);
            if (aHasLo) {
#pragma unroll
                for (int i = 0; i < 4; i++)
                    aLo[i] = *(const s16x8*)((const char*)As + aoffL[i]);
            }
#pragma unroll
            for (int j = 0; j < 4; j++) {
                s16x8 bHi = *(const s16x8*)((const char*)Bs + boffH[j]);
#pragma unroll
                for (int i = 0; i < 4; i++)
                    acc[i][j] = __builtin_amdgcn_mfma_f32_16x16x32_bf16(
                        aHi[i], bHi, acc[i][j], 0, 0, 0);
                if (bHasLo) {
                    s16x8 bLo = *(const s16x8*)((const char*)Bs + boffL[j]);
#pragma unroll
                    for (int i = 0; i < 4; i++)
                        acc[i][j] = __builtin_amdgcn_mfma_f32_16x16x32_bf16(
                            aHi[i], bLo, acc[i][j], 0, 0, 0);
                }
                if (aHasLo) {
#pragma unroll
                    for (int i = 0; i < 4; i++)
                        acc[i][j] = __builtin_amdgcn_mfma_f32_16x16x32_bf16(
                            aLo[i], bHi, acc[i][j], 0, 0, 0);
                }
            }
        }
    } else {
        // ----- slow path: fp32 operands (fallback model dtype) -----
        for (int k0 = kBeg; k0 < kEnd; k0 += 32) {
            __syncthreads();
            {   // stage A
                char* rowp = (char*)&As[sr][0];
                long aoff = (long)agr * lda + k0 + sh * 16;
                if (am == 2)      stage_pair_row(aH + aoff, aL + aoff, rowp, sh, sr);
                else if (am == 1) stage_bf16_row(aH + aoff, rowp, sh, sr);
                else              stage_f32_row (aF + aoff, rowp, sh, sr);
            }
            // stage B
            if (NT) {
                char* rowp = (char*)&Bs[sr][0];
                long boff = (long)(n0 + sr) * ldb + k0 + sh * 16;
                if (bm == 2)      stage_pair_row(bH + boff, bL + boff, rowp, sh, sr);
                else if (bm == 1) stage_bf16_row(bH + boff, rowp, sh, sr);
                else              stage_f32_row (bF + boff, rowp, sh, sr);
            } else {
                long boff = (long)(k0 + kp2) * ldb + n0 + n8;
                if (bm == 2) {
                    stage_wnn_bf16(bH + boff, ldb, Bs, kp2, n8, 0);
                    stage_wnn_bf16(bL + boff, ldb, Bs, kp2, n8, 64);
                } else if (bm == 1) {
                    stage_wnn_bf16(bH + boff, ldb, Bs, kp2, n8, 0);
                } else {
                    stage_wnn_f32 (bF + boff, ldb, Bs, kp2, n8);
                }
            }
            __syncthreads();

            s16x8 aHi[4], aLo[4];
#pragma unroll
            for (int i = 0; i < 4; i++)
                aHi[i] = *(const s16x8*)((const char*)As + aoffH[i]);
            if (aHasLo) {
#pragma unroll
                for (int i = 0; i < 4; i++)
                    aLo[i] = *(const s16x8*)((const char*)As + aoffL[i]);
            }
#pragma unroll
            for (int j = 0; j < 4; j++) {
                s16x8 bHi = *(const s16x8*)((const char*)Bs + boffH[j]);
#pragma unroll
                for (int i = 0; i < 4; i++)
                    acc[i][j] = __builtin_amdgcn_mfma_f32_16x16x32_bf16(
                        aHi[i], bHi, acc[i][j], 0, 0, 0);
                if (bHasLo) {
                    s16x8 bLo = *(const s16x8*)((const char*)Bs + boffL[j]);
#pragma unroll
                    for (int i = 0; i < 4; i++)
                        acc[i][j] = __builtin_amdgcn_mfma_f32_16x16x32_bf16(
                            aHi[i], bLo, acc[i][j], 0, 0, 0);
                }
                if (aHasLo) {
#pragma unroll
                    for (int i = 0; i < 4; i++)
                        acc[i][j] = __builtin_amdgcn_mfma_f32_16x16x32_bf16(
                            aLo[i], bHi, acc[i][j], 0, 0, 0);
                }
            }
        }
    }

    // epilogue: C/D layout col=lane&15, row=(lane>>4)*4+reg
#pragma unroll
    for (int j = 0; j < 4; j++) {
        int col = n0 + wc * 64 + j * 16 + lr;
        float bv = 0.f;
        if (hasb) bv = bf ? bf2f(biasH[col]) : biasF[col];
#pragma unroll
        for (int i = 0; i < 4; i++) {
#pragma unroll
            for (int rr = 0; rr < 4; rr++) {
                int grow = m0 + wr * 64 + i * 16 + kg * 4 + rr;
                if (GATHER && grow >= Meff) continue;
                int crow = GATHER ? gl[grow] : grow;
                float v = acc[i][j][rr] + bv;
                if (RELU) v = fmaxf(v, 0.f);
                if (SCALE) v *= scalev[crow];
                if (OUTP) {
                    bf16_t hh, ll;
                    split_rne(v, hh, ll);
                    long off = (long)crow * ldc + col;
                    CpH[off] = hh;
                    CpH[cplane + off] = ll;
                } else {
                    Cp[(long)crow * ldc + col] = v;
                }
            }
        }
    }
}

// ---------------- generic wrapper -------------------------------------------
template<bool NT, bool RELU, bool GATHER, bool SCALE,
         bool MASK_TRI, bool MASK_K, bool SPLITK, bool OUTP>
__global__ __launch_bounds__(256, 2)
void mgemm_kernel(int amode, int bmode,
                  const void* a32, const void* a16, const void* a16lo,
                  const void* b32, const void* b16, const void* b16lo,
                  const void* bias32, const void* bias16,
                  float* C, void* CH, long cplane,
                  int M, int N, int K, int lda, int ldb, int ldc,
                  long aZ, long bZ, long biasZ, long cZ,
                  const int* __restrict__ glist, const int* __restrict__ counts,
                  const float* __restrict__ scalev,
                  const int* __restrict__ dtf)
{
    if (MASK_TRI && blockIdx.x > blockIdx.y) return;
    const int e  = SPLITK ? 0 : blockIdx.z;
    const int n0 = blockIdx.x * 128, m0 = blockIdx.y * 128;
    int Meff = M;
    const int* gl = nullptr;
    if (GATHER) {
        gl = glist + e * 4096;
        Meff = counts[e];
        if (m0 >= Meff) return;          // whole-block uniform, before barriers
    }
    const bool bf = (*dtf != 0);
    const int am = (amode < 0) ? (bf ? 1 : 0) : amode;
    const int bm = (bmode < 0) ? (bf ? 1 : 0) : bmode;

    const float*  aF = (const float*)a32 + (long)e * aZ;
    const bf16_t* aH = (const bf16_t*)a16 + (long)e * aZ;
    const bf16_t* aL = (const bf16_t*)a16lo + (long)e * aZ;
    const long bOff  = SPLITK ? 0 : (long)e * bZ;
    const float*  bF = (const float*)b32 + bOff;
    const bf16_t* bH = (const bf16_t*)b16 + bOff;
    const bf16_t* bL = (const bf16_t*)b16lo + bOff;

    float* Cp = nullptr;
    bf16_t* CpH = nullptr;
    int kBeg = 0, kEnd = K;
    if (SPLITK) {
        const int kc  = blockIdx.z;
        const int kch = (int)bZ;          // bZ reused as K-chunk size
        kBeg = kc * kch;
        kEnd = kBeg + kch;
        Cp = C + (long)kc * cZ;           // cZ = partial-plane stride
    } else {
        if (C)  Cp  = C + (long)e * cZ;
        if (CH) CpH = (bf16_t*)CH + (long)e * cZ;
        if (MASK_K) kEnd = (blockIdx.y + 1) * 128;
    }
    const bool hasb = !SPLITK && ((bias32 != nullptr) || (bias16 != nullptr));
    const float*  biasF = (const float*)bias32 + (long)e * biasZ;
    const bf16_t* biasH = (const bf16_t*)bias16 + (long)e * biasZ;

    mgemm_body<NT, RELU, GATHER, SCALE, OUTP>(am, aF, aH, aL, bm, bF, bH, bL,
        biasF, biasH, bf, hasb, Cp, CpH, cplane, lda, ldb, ldc, Meff, gl,
        scalev, kBeg, kEnd, m0, n0);
}

// ---------------- fused Q/K/V wrapper ---------------------------------------
struct TriArgs {
    const void* aF[3]; const void* aH[3]; const void* aL[3];
    const void* w32[3]; const void* w16[3];
    const void* b32[3]; const void* b16[3];
    void* dstH[3];
    int am[3];          // -1 = input dtype, 2 = ws pair
};

__global__ __launch_bounds__(256, 2)
void mgemm_tri_kernel(TriArgs ta, const int* __restrict__ dtf)
{
    const int z = blockIdx.z;
    const bool bf = (*dtf != 0);
    const int am = (ta.am[z] < 0) ? (bf ? 1 : 0) : ta.am[z];
    const int bm = bf ? 1 : 0;
    mgemm_body<false, false, false, false, true>(
        am, (const float*)ta.aF[z], (const bf16_t*)ta.aH[z], (const bf16_t*)ta.aL[z],
        bm, (const float*)ta.w32[z], (const bf16_t*)ta.w16[z], nullptr,
        (const float*)ta.b32[z], (const bf16_t*)ta.b16[z],
        bf, true,
        nullptr, (bf16_t*)ta.dstH[z], 4194304L,
        512, 4096, 4096,
        0, nullptr, nullptr,
        0, 512, blockIdx.y * 128, blockIdx.x * 128);
}

// ---------------- split-K reduce (+bias) ------------------------------------
template<int NCH>
__global__ __launch_bounds__(256)
void reduce_kernel(const float* __restrict__ part,
                   const void* bias32, const void* bias16,
                   float* __restrict__ out, const int* __restrict__ dtf)
{
    const bool bf = (*dtf != 0);
    const int i = (blockIdx.x * 256 + threadIdx.x) * 4;   // over 1024*512
    float4 s = *(const float4*)(part + i);
#pragma unroll
    for (int c = 1; c < NCH; c++) {
        float4 p = *(const float4*)(part + (long)c * 524288 + i);
        s.x += p.x; s.y += p.y; s.z += p.z; s.w += p.w;
    }
    const int col = i & 511;
    float b0, b1, b2, b3;
    if (bf) {
        const bf16_t* bb = (const bf16_t*)bias16;
        b0 = bf2f(bb[col]); b1 = bf2f(bb[col + 1]);
        b2 = bf2f(bb[col + 2]); b3 = bf2f(bb[col + 3]);
    } else {
        const float* bb = (const float*)bias32;
        b0 = bb[col]; b1 = bb[col + 1]; b2 = bb[col + 2]; b3 = bb[col + 3];
    }
    out[i + 0] = s.x + b0; out[i + 1] = s.y + b1;
    out[i + 2] = s.z + b2; out[i + 3] = s.w + b3;
}

// ---------------- Attention phase 2: softmax fp32 -> bf16 pair (in place) ---
// Row layout after this kernel: 4KB row = [hi bf16 x1024 | lo bf16 x1024].
template<bool MASKED>
__global__ __launch_bounds__(256)
void softmax_kernel(float* __restrict__ sb)
{
    const int g = blockIdx.x * 4 + (threadIdx.x >> 6);
    const int lane = threadIdx.x & 63;
    const int r = g & 1023;
    float* row = sb + (long)g * 1024;
    bf16_t* rowh = (bf16_t*)row;
    const int n = MASKED ? (r + 1) : 1024;

    float vv[16];
    float m = -1e30f;
#pragma unroll
    for (int j = 0; j < 4; j++) {
        float4 v4 = *(const float4*)(row + j * 256 + lane * 4);
        const float* pv = (const float*)&v4;
#pragma unroll
        for (int c = 0; c < 4; c++) {
            int idx = j * 256 + lane * 4 + c;
            float x = (idx < n) ? pv[c] : -1e30f;
            vv[j * 4 + c] = x;
            m = fmaxf(m, x);
        }
    }
    m = waveReduceMax(m);
    float sum = 0.0f;
#pragma unroll
    for (int i = 0; i < 16; i++) {
        vv[i] = __expf(vv[i] - m);
        sum += vv[i];
    }
    sum = waveReduceSum(sum);
    float inv = 1.0f / sum;
#pragma unroll
    for (int j = 0; j < 4; j++) {
        ushort4 hh, ll;
        float p0 = vv[j * 4 + 0] * inv, p1 = vv[j * 4 + 1] * inv;
        float p2 = vv[j * 4 + 2] * inv, p3 = vv[j * 4 + 3] * inv;
        bf16_t h, l;
        split_rne(p0, h, l); hh.x = h; ll.x = l;
        split_rne(p1, h, l); hh.y = h; ll.y = l;
        split_rne(p2, h, l); hh.z = h; ll.z = l;
        split_rne(p3, h, l); hh.w = h; ll.w = l;
        *(ushort4*)(rowh + (j * 256 + lane * 4)) = hh;
        *(ushort4*)(rowh + 1024 + (j * 256 + lane * 4)) = ll;
    }
}

// ---------------- Fallback flash (small-ws path) ----------------------------
template<bool MASKED>
__global__ __launch_bounds__(256)
void flash_kernel(const bf16_t* __restrict__ qh, const bf16_t* __restrict__ ql,
                  const bf16_t* __restrict__ kh, const bf16_t* __restrict__ kl,
                  const bf16_t* __restrict__ vh, const bf16_t* __restrict__ vl,
                  bf16_t* __restrict__ outH)
{
    const int h = blockIdx.y;
    const long bh = (long)h * 524288L;
    const int t = threadIdx.x, lane = t & 63, wave = t >> 6;
    const int base = blockIdx.x * 32;
    const int row0 = base + wave * 8;

    float qreg[8][8], oacc[8][8];
    float mi[8], li[8];
#pragma unroll
    for (int i = 0; i < 8; i++) {
        mi[i] = -1e30f;
        li[i] = 0.0f;
#pragma unroll
        for (int d = 0; d < 8; d++) {
            long idx = bh + (long)(row0 + i) * 512 + lane + 64 * d;
            qreg[i][d] = bf2f(qh[idx]) + bf2f(ql[idx]);
            oacc[i][d] = 0.0f;
        }
    }

    __shared__ float ks[8][512];
    __shared__ float vs[8][512];

    const int kmax = MASKED ? (base + 31) : 1023;
    for (int k0 = 0; k0 <= kmax; k0 += 8) {
        __syncthreads();
#pragma unroll
        for (int r = 0; r < 4; r++) {
            int flat = (r * 256 + t) * 4;
            int kr = flat >> 9, col = flat & 511;
            long idx = bh + (long)(k0 + kr) * 512 + col;
            ushort4 kh4 = *(const ushort4*)&kh[idx];
            ushort4 kl4 = *(const ushort4*)&kl[idx];
            ushort4 vh4 = *(const ushort4*)&vh[idx];
            ushort4 vl4 = *(const ushort4*)&vl[idx];
            ks[kr][col + 0] = bf2f(kh4.x) + bf2f(kl4.x);
            ks[kr][col + 1] = bf2f(kh4.y) + bf2f(kl4.y);
            ks[kr][col + 2] = bf2f(kh4.z) + bf2f(kl4.z);
            ks[kr][col + 3] = bf2f(kh4.w) + bf2f(kl4.w);
            vs[kr][col + 0] = bf2f(vh4.x) + bf2f(vl4.x);
            vs[kr][col + 1] = bf2f(vh4.y) + bf2f(vl4.y);
            vs[kr][col + 2] = bf2f(vh4.z) + bf2f(vl4.z);
            vs[kr][col + 3] = bf2f(vh4.w) + bf2f(vl4.w);
        }
        __syncthreads();
#pragma unroll
        for (int j = 0; j < 8; j++) {
            const int kg = k0 + j;
#pragma unroll
            for (int i = 0; i < 8; i++) {
                const int qrow = row0 + i;
                if (MASKED && kg > qrow) continue;
                float p = 0.0f;
#pragma unroll
                for (int d = 0; d < 8; d++)
                    p = fmaf(qreg[i][d], ks[j][lane + 64 * d], p);
                p = waveReduceSum(p);
                float mnew = fmaxf(mi[i], p);
                float sc = __expf(mi[i] - mnew);
                float pe = __expf(p - mnew);
                li[i] = li[i] * sc + pe;
                mi[i] = mnew;
#pragma unroll
                for (int d = 0; d < 8; d++)
                    oacc[i][d] = fmaf(oacc[i][d], sc, pe * vs[j][lane + 64 * d]);
            }
        }
    }

#pragma unroll
    for (int i = 0; i < 8; i++) {
        float inv = 1.0f / li[i];
#pragma unroll
        for (int d = 0; d < 8; d++) {
            long off = (long)(row0 + i) * 4096 + h * 512 + lane + 64 * d;
            bf16_t hh, ll;
            split_rne(oacc[i][d] * inv, hh, ll);
            outH[off] = hh;
            outH[4194304L + off] = ll;
        }
    }
}

// ---------------- Fused residual add + LayerNorm ----------------------------
// RM: 0 = residual in model dtype, 1 = residual is ws bf16 pair.
// OM: 0 = output in model dtype, 1 = output is ws bf16 pair.
template<int RM, int OM>
__global__ __launch_bounds__(256)
void add_ln_kernel(const float* __restrict__ a,
                   const void* r32, const void* r16, const void* r16lo,
                   const void* g32, const void* g16,
                   const void* b32, const void* b16,
                   void* out, void* outLo, const int* __restrict__ dtf)
{
    const bool bf = (*dtf != 0);
    const int row = blockIdx.x, t = threadIdx.x;
    const long o = (long)row * 512;

    float r0, r1;
    if (RM == 1) {
        const bf16_t* rh = (const bf16_t*)r16;
        const bf16_t* rl = (const bf16_t*)r16lo;
        r0 = bf2f(rh[o + t]) + bf2f(rl[o + t]);
        r1 = bf2f(rh[o + 256 + t]) + bf2f(rl[o + 256 + t]);
    } else if (bf) {
        r0 = bf2f(((const bf16_t*)r16)[o + t]);
        r1 = bf2f(((const bf16_t*)r16)[o + 256 + t]);
    } else {
        r0 = ((const float*)r32)[o + t];
        r1 = ((const float*)r32)[o + 256 + t];
    }
    float z0 = a[o + t] + r0;
    float z1 = a[o + 256 + t] + r1;

    __shared__ float red[4];
    const int lane = t & 63, wave = t >> 6;

    float s = waveReduceSum(z0 + z1);
    if (lane == 0) red[wave] = s;
    __syncthreads();
    float mean = (red[0] + red[1] + red[2] + red[3]) * (1.0f / 512.0f);
    float d0 = z0 - mean, d1 = z1 - mean;
    float vsum = waveReduceSum(d0 * d0 + d1 * d1);
    __syncthreads();
    if (lane == 0) red[wave] = vsum;
    __syncthreads();
    float var = (red[0] + red[1] + red[2] + red[3]) * (1.0f / 512.0f);
    float rstd = rsqrtf(var + 1e-5f);

    float gg0, gg1, bb0, bb1;
    if (bf) {
        gg0 = bf2f(((const bf16_t*)g16)[t]);  gg1 = bf2f(((const bf16_t*)g16)[t + 256]);
        bb0 = bf2f(((const bf16_t*)b16)[t]);  bb1 = bf2f(((const bf16_t*)b16)[t + 256]);
    } else {
        gg0 = ((const float*)g32)[t];         gg1 = ((const float*)g32)[t + 256];
        bb0 = ((const float*)b32)[t];         bb1 = ((const float*)b32)[t + 256];
    }
    float o0 = gg0 * d0 * rstd + bb0;
    float o1 = gg1 * d1 * rstd + bb1;
    if (OM == 1) {
        bf16_t* oh = (bf16_t*)out;
        bf16_t* ol = (bf16_t*)outLo;
        bf16_t hh, ll;
        split_rne(o0, hh, ll); oh[o + t] = hh;        ol[o + t] = ll;
        split_rne(o1, hh, ll); oh[o + 256 + t] = hh;  ol[o + 256 + t] = ll;
    } else if (bf) {
        ((bf16_t*)out)[o + t] = f2bf(o0);
        ((bf16_t*)out)[o + 256 + t] = f2bf(o1);
    } else {
        ((float*)out)[o + t] = o0;
        ((float*)out)[o + 256 + t] = o1;
    }
}

// ---------------- Gating (x is bf16 pair) -----------------------------------
__global__ __launch_bounds__(256)
void gate_kernel(const bf16_t* __restrict__ xh, const bf16_t* __restrict__ xl,
                 const void* gw32, const void* gw16,
                 const void* gb32, const void* gb16,
                 int* __restrict__ sel, float* __restrict__ wsel,
                 const int* __restrict__ dtf)
{
    const bool bf = (*dtf != 0);
    const int lane = threadIdx.x & 63, wave = threadIdx.x >> 6;
    const int token = blockIdx.x * 4 + wave;
    float xr[8];
#pragma unroll
    for (int i = 0; i < 8; i++) {
        long idx = (long)token * 512 + lane + 64 * i;
        xr[i] = bf2f(xh[idx]) + bf2f(xl[idx]);
    }
    float logits[8];
#pragma unroll
    for (int e = 0; e < 8; e++) {
        float p = 0.0f;
#pragma unroll
        for (int i = 0; i < 8; i++) {
            long idx = (long)(lane + 64 * i) * 8 + e;
            float w = bf ? bf2f(((const bf16_t*)gw16)[idx]) : ((const float*)gw32)[idx];
            p = fmaf(xr[i], w, p);
        }
        p = waveReduceSum(p);
        float b = bf ? bf2f(((const bf16_t*)gb16)[e]) : ((const float*)gb32)[e];
        logits[e] = p + b;
    }
    if (lane == 0) {
        float m1 = -1e30f, m2 = -1e30f;
        int i1 = 0, i2 = 0;
#pragma unroll
        for (int e = 0; e < 8; e++) {
            float vv = logits[e];
            if (vv > m1) { m2 = m1; i2 = i1; m1 = vv; i1 = e; }
            else if (vv > m2) { m2 = vv; i2 = e; }
        }
        float ed = __expf(m2 - m1);
        sel[token]  = i2;
        wsel[token] = ed / (1.0f + ed);
    }
}

__global__ void zero_counts_kernel(int* __restrict__ counts)
{
    if (threadIdx.x < 8) counts[threadIdx.x] = 0;
}

__global__ __launch_bounds__(256)
void route_kernel(const int* __restrict__ sel, int* __restrict__ counts,
                  int* __restrict__ idx)
{
    int tk = blockIdx.x * 256 + threadIdx.x;
    int e = sel[tk] & 7;
    int pos = atomicAdd(&counts[e], 1) & 4095;
    idx[e * 4096 + pos] = tk;
}

// ---------------------------------------------------------------------------
extern "C" void kernel_launch(void* const* d_in, const int* in_sizes, int n_in,
                              void* d_out, int out_size, void* d_ws, size_t ws_size,
                              hipStream_t stream)
{
    const char* x_in = (const char*)d_in[0];
    const char* enc  = (const char*)d_in[1];
    const char* wq   = (const char*)d_in[2];
    const char* bq   = (const char*)d_in[3];
    const char* wk   = (const char*)d_in[4];
    const char* bk   = (const char*)d_in[5];
    const char* wv   = (const char*)d_in[6];
    const char* bv   = (const char*)d_in[7];
    const char* wo   = (const char*)d_in[8];
    const char* bo   = (const char*)d_in[9];
    const char* gw   = (const char*)d_in[10];
    const char* gb   = (const char*)d_in[11];
    const char* ew1  = (const char*)d_in[12];
    const char* eb1  = (const char*)d_in[13];
    const char* ew2  = (const char*)d_in[14];
    const char* eb2  = (const char*)d_in[15];
    const char* lng  = (const char*)d_in[16];
    const char* lnb  = (const char*)d_in[17];

    float* ws = (float*)d_ws;
    const long SZ_X = 4096L * 512;
    const long SZ_B = 1024L * 4096;
    float* xb = ws;
    float* ab = xb + SZ_X;
    float* qb = ab + SZ_X;
    float* kb = qb + SZ_B;
    float* vb = kb + SZ_B;
    float* cb = vb + SZ_B;
    float* h1 = qb;                  // aliases qb (dead during MoE)
    float* yb = kb;                  // aliases kb (dead during MoE)
    float* wselp = cb + SZ_B;
    int* selp   = (int*)(wselp + 4096);
    int* counts = selp + 4096;
    int* idxl   = counts + 8;
    int* dtf    = idxl + 8 * 4096;
    long sb_off = (((long)(dtf + 1 - (int*)ws)) + 3) & ~3L;
    float* sbuf = ws + sb_off;
    const long NEED = (sb_off + 8L * 1048576L) * 4L;   // bytes
    const bool big = (ws_size >= (size_t)NEED);

    // bf16 pair plane views (hi plane at base, lo plane at +plane elements)
    bf16_t* xh  = (bf16_t*)xb;   bf16_t* xl  = xh + 2097152;   // [4096,512]
    bf16_t* qh  = (bf16_t*)qb;   bf16_t* ql  = qh + 4194304;   // [1024,4096]
    bf16_t* kh  = (bf16_t*)kb;   bf16_t* kl  = kh + 4194304;
    bf16_t* vh  = (bf16_t*)vb;   bf16_t* vl  = vh + 4194304;
    bf16_t* cbh = (bf16_t*)cb;   bf16_t* cbl = cbh + 4194304;
    bf16_t* h1h = (bf16_t*)h1;   bf16_t* h1l = h1h + 4194304;  // [4096,1024]
    bf16_t* sbh = (bf16_t*)sbuf;                               // pair-per-row

    dim3 blk(256);
    const long SB = 1024L * 512;     // per-batch elements of x/enc
    const long L3 = 512L * 4096;     // per-(l,att) elements of wq/wk/wv
    const long LO = 4096L * 512;     // per-(l,att) elements of wo

    probe_kernel<<<1, 64, 0, stream>>>((const unsigned int*)lng, dtf);

    const char* cur = x_in;
    bool cur_is_ws = false;

    for (int l = 0; l < 2; l++) {
        for (int att = 0; att < 2; att++) {
            const long woff = (long)(l * 2 + att);
            const void* Wx32[4] = { wq + woff * L3 * 4, wk + woff * L3 * 4,
                                    wv + woff * L3 * 4, wo + woff * LO * 4 };
            const void* Wx16[4] = { wq + woff * L3 * 2, wk + woff * L3 * 2,
                                    wv + woff * L3 * 2, wo + woff * LO * 2 };
            const void* Bx32[4] = { bq + woff * 4096 * 4, bk + woff * 4096 * 4,
                                    bv + woff * 4096 * 4, bo + woff * 512 * 4 };
            const void* Bx16[4] = { bq + woff * 4096 * 2, bk + woff * 4096 * 2,
                                    bv + woff * 4096 * 2, bo + woff * 512 * 2 };

            for (int b = 0; b < 4; b++) {
                const bool aqk_in = (att == 1) || !cur_is_ws;
                void* dst3[3] = { qb, kb, vb };

                TriArgs ta;
                for (int m = 0; m < 3; m++) {
                    const bool a_in = (m == 2) ? !cur_is_ws : aqk_in;
                    if (a_in) {
                        const char* Asrc = (m == 2) ? x_in : ((att == 1) ? enc : x_in);
                        ta.am[m] = -1;
                        ta.aF[m] = Asrc + b * SB * 4;
                        ta.aH[m] = Asrc + b * SB * 2;
                        ta.aL[m] = nullptr;
                    } else {
                        ta.am[m] = 2;
                        ta.aF[m] = nullptr;
                        ta.aH[m] = xh + b * SB;
                        ta.aL[m] = xl + b * SB;
                    }
                    ta.w32[m] = Wx32[m]; ta.w16[m] = Wx16[m];
                    ta.b32[m] = Bx32[m]; ta.b16[m] = Bx16[m];
                    ta.dstH[m] = dst3[m];
                }
                mgemm_tri_kernel<<<dim3(32, 8, 3), blk, 0, stream>>>(ta, dtf);

                if (big) {
                    if (att == 0) {
                        mgemm_kernel<true, false, false, false, true, false, false, false>
                            <<<dim3(8, 8, 8), blk, 0, stream>>>(
                            2, 2, nullptr, qh, ql, nullptr, kh, kl,
                            nullptr, nullptr, sbuf, nullptr, 0,
                            1024, 1024, 512, 512, 512, 1024,
                            524288L, 524288L, 0, 1048576L,
                            nullptr, nullptr, nullptr, dtf);
                        softmax_kernel<true><<<2048, blk, 0, stream>>>(sbuf);
                        mgemm_kernel<false, false, false, false, false, true, false, true>
                            <<<dim3(4, 8, 8), blk, 0, stream>>>(
                            2, 2, nullptr, sbh, sbh + 1024, nullptr, vh, vl,
                            nullptr, nullptr, nullptr, cbh, 4194304L,
                            1024, 512, 1024, 2048, 512, 4096,
                            2097152L, 524288L, 0, 512L,
                            nullptr, nullptr, nullptr, dtf);
                    } else {
                        mgemm_kernel<true, false, false, false, false, false, false, false>
                            <<<dim3(8, 8, 8), blk, 0, stream>>>(
                            2, 2, nullptr, qh, ql, nullptr, kh, kl,
                            nullptr, nullptr, sbuf, nullptr, 0,
                            1024, 1024, 512, 512, 512, 1024,
                            524288L, 524288L, 0, 1048576L,
                            nullptr, nullptr, nullptr, dtf);
                        softmax_kernel<false><<<2048, blk, 0, stream>>>(sbuf);
                        mgemm_kernel<false, false, false, false, false, false, false, true>
                            <<<dim3(4, 8, 8), blk, 0, stream>>>(
                            2, 2, nullptr, sbh, sbh + 1024, nullptr, vh, vl,
                            nullptr, nullptr, nullptr, cbh, 4194304L,
                            1024, 512, 1024, 2048, 512, 4096,
                            2097152L, 524288L, 0, 512L,
                            nullptr, nullptr, nullptr, dtf);
                    }
                    // out-proj split-K: 16 chunks of K=256 -> partials in sbuf
                    mgemm_kernel<false, false, false, false, false, false, true, false>
                        <<<dim3(4, 8, 16), blk, 0, stream>>>(
                        2, -1, nullptr, cbh, cbl, Wx32[3], Wx16[3], nullptr,
                        nullptr, nullptr, sbuf, nullptr, 0,
                        1024, 512, 4096, 4096, 512, 512,
                        0, 256 /*K-chunk*/, 0, 524288L /*plane stride*/,
                        nullptr, nullptr, nullptr, dtf);
                    reduce_kernel<16><<<512, blk, 0, stream>>>(
                        sbuf, Bx32[3], Bx16[3], ab + b * SB, dtf);
                } else {
                    if (att == 0)
                        flash_kernel<true><<<dim3(32, 8), blk, 0, stream>>>(
                            qh, ql, kh, kl, vh, vl, cbh);
                    else
                        flash_kernel<false><<<dim3(32, 8), blk, 0, stream>>>(
                            qh, ql, kh, kl, vh, vl, cbh);
                    mgemm_kernel<false, false, false, false, false, false, false, false>
                        <<<dim3(4, 8, 1), blk, 0, stream>>>(
                        2, -1, nullptr, cbh, cbl, Wx32[3], Wx16[3], nullptr,
                        Bx32[3], Bx16[3], ab + b * SB, nullptr, 0,
                        1024, 512, 4096, 4096, 512, 512,
                        0, 0, 0, 0, nullptr, nullptr, nullptr, dtf);
                }
            }

            const void* G32  = lng + (long)(l * 3 + att) * 512 * 4;
            const void* G16  = lng + (long)(l * 3 + att) * 512 * 2;
            const void* Bt32 = lnb + (long)(l * 3 + att) * 512 * 4;
            const void* Bt16 = lnb + (long)(l * 3 + att) * 512 * 2;
            if (cur_is_ws)
                add_ln_kernel<1, 1><<<4096, blk, 0, stream>>>(
                    ab, nullptr, xh, xl, G32, G16, Bt32, Bt16, xh, xl, dtf);
            else
                add_ln_kernel<0, 1><<<4096, blk, 0, stream>>>(
                    ab, (const void*)cur, (const void*)cur, nullptr,
                    G32, G16, Bt32, Bt16, xh, xl, dtf);
            cur = (const char*)xb; cur_is_ws = true;
        }

        // ---- MoE ----
        gate_kernel<<<1024, blk, 0, stream>>>(
            xh, xl, gw + (long)l * 512 * 8 * 4, gw + (long)l * 512 * 8 * 2,
            gb + (long)l * 8 * 4, gb + (long)l * 8 * 2, selp, wselp, dtf);
        zero_counts_kernel<<<1, 64, 0, stream>>>(counts);
        route_kernel<<<16, blk, 0, stream>>>(selp, counts, idxl);

        mgemm_kernel<false, true, true, false, false, false, false, true>
            <<<dim3(8, 32, 8), blk, 0, stream>>>(
            2, -1, nullptr, xh, xl,
            ew1 + (long)l * 8 * 512 * 1024 * 4, ew1 + (long)l * 8 * 512 * 1024 * 2,
            nullptr,
            eb1 + (long)l * 8 * 1024 * 4, eb1 + (long)l * 8 * 1024 * 2,
            nullptr, h1h, 4194304L,
            4096, 1024, 512, 512, 1024, 1024,
            0, 512L * 1024, 1024, 0, idxl, counts, nullptr, dtf);
        mgemm_kernel<false, false, true, true, false, false, false, false>
            <<<dim3(4, 32, 8), blk, 0, stream>>>(
            2, -1, nullptr, h1h, h1l,
            ew2 + (long)l * 8 * 1024 * 512 * 4, ew2 + (long)l * 8 * 1024 * 512 * 2,
            nullptr,
            eb2 + (long)l * 8 * 512 * 4, eb2 + (long)l * 8 * 512 * 2,
            yb, nullptr, 0,
            4096, 512, 1024, 1024, 512, 512,
            0, 1024L * 512, 512, 0, idxl, counts, wselp, dtf);

        const void* G32  = lng + (long)(l * 3 + 2) * 512 * 4;
        const void* G16  = lng + (long)(l * 3 + 2) * 512 * 2;
        const void* Bt32 = lnb + (long)(l * 3 + 2) * 512 * 4;
        const void* Bt16 = lnb + (long)(l * 3 + 2) * 512 * 2;
        if (l == 0)
            add_ln_kernel<1, 1><<<4096, blk, 0, stream>>>(
                yb, nullptr, xh, xl, G32, G16, Bt32, Bt16, xh, xl, dtf);
        else
            add_ln_kernel<1, 0><<<4096, blk, 0, stream>>>(
                yb, nullptr, xh, xl, G32, G16, Bt32, Bt16, d_out, nullptr, dtf);
    }
}